// Round 5
// baseline (293.921 us; speedup 1.0000x reference)
//
#include <hip/hip_runtime.h>
#include <hip/hip_bf16.h>
#include <math.h>

typedef __bf16 bf16x8 __attribute__((ext_vector_type(8)));
typedef float f32x4 __attribute__((ext_vector_type(4)));
typedef unsigned short u16x8 __attribute__((ext_vector_type(8)));
typedef unsigned short u16x4 __attribute__((ext_vector_type(4)));

static __device__ __forceinline__ unsigned short f2bf(float f) {
    union { float f; unsigned u; } v; v.f = f;
    unsigned r = v.u + 0x7fffu + ((v.u >> 16) & 1u);
    return (unsigned short)(r >> 16);
}

static __device__ __forceinline__ float exp2fast(float x) {
    return __builtin_exp2f(x);   // v_exp_f32; avoids glibc __exp2f macro clash
}

static __device__ __forceinline__ void gload16(const void* g, void* l) {
    __builtin_amdgcn_global_load_lds((const __attribute__((address_space(1))) unsigned int*)g,
                                     (__attribute__((address_space(3))) unsigned int*)l, 16, 0, 0);
}

#define MFMA16(a, b, c) __builtin_amdgcn_mfma_f32_16x16x32_bf16((a), (b), (c), 0, 0, 0)

// read a bf16x8 fragment from a chunk-XOR-swizzled tile with 128B rows
static __device__ __forceinline__ bf16x8 frag_swz(const unsigned short* base, int row, int chunk) {
    return *(const bf16x8*)((const char*)base + row * 128 + (((chunk ^ row) & 7) << 4));
}

// ---------------------------------------------------------------------------
// prep: fused fp32->bf16 for 3 activation tensors (blocks 0..6143) and
// W[k][n] -> Wt bf16 [n][k] transpose for 4 weights (blocks 6144..7167).
// ---------------------------------------------------------------------------
struct PrepArgs {
    const float* act[3]; unsigned short* actout[3];
    const float* W[4];   unsigned short* Wt[4];
};

__global__ void prep_kernel(PrepArgs a) {
    __shared__ __align__(16) unsigned short Ws[64][66];
    const int b = blockIdx.x, t = threadIdx.x;
    if (b < 6144) {
        const int sel = b >> 11;
        const size_t i = (((size_t)(b & 2047)) * 256 + t) * 8;
        const float* in = a.act[sel];
        f32x4 v0 = *(const f32x4*)(in + i);
        f32x4 v1 = *(const f32x4*)(in + i + 4);
        u16x8 o;
#pragma unroll
        for (int j = 0; j < 4; ++j) { o[j] = f2bf(v0[j]); o[j + 4] = f2bf(v1[j]); }
        *(u16x8*)(a.actout[sel] + i) = o;
        return;
    }
    const int idx = b - 6144;              // 0..1023
    const int z = idx >> 8;                // weight id
    const int rem = idx & 255;
    const int c0 = (rem & 15) * 64;        // n base
    const int r0 = (rem >> 4) * 64;        // k base
    const float* W = a.W[z];
    unsigned short* Wt = a.Wt[z];
#pragma unroll
    for (int p = 0; p < 4; ++p) {
        int lin = p * 256 + t;
        int r = lin >> 4, cc = (lin & 15) * 4;
        f32x4 v = *(const f32x4*)(W + (size_t)(r0 + r) * 1024 + c0 + cc);
#pragma unroll
        for (int j = 0; j < 4; ++j) Ws[r][cc + j] = f2bf(v[j]);
    }
    __syncthreads();
#pragma unroll
    for (int p = 0; p < 2; ++p) {
        int lin = p * 256 + t;
        int n = lin >> 3, kc = (lin & 7) * 8;
        u16x8 o;
#pragma unroll
        for (int j = 0; j < 8; ++j) o[j] = Ws[kc + j][n];
        *(u16x8*)(Wt + (size_t)(c0 + n) * 1024 + r0 + kc) = o;
    }
}

// ---------------------------------------------------------------------------
// Fused QKV projection: grid (8, 32, 3); z selects {Q,K,V}.
// 128x128 tile, BK=64, single-buffered LDS (32KB) -> 3 blocks/CU.
// z<2: out bf16 (B,H,S,HD) scaled; z==2: out bf16 (B,H,HD,S).
// ---------------------------------------------------------------------------
struct QkvArgs {
    const unsigned short* A[3];
    const unsigned short* Wt[3];
    const float* bias[3];
    unsigned short* out[3];
    float scale[3];
};

__global__ __launch_bounds__(256, 3)
void gemm_qkv(QkvArgs p)
{
    __shared__ __align__(16) unsigned short As[128 * 64];
    __shared__ __align__(16) unsigned short Bs[128 * 64];

    const int z = blockIdx.z;
    const unsigned short* A  = p.A[z];
    const unsigned short* Bt = p.Wt[z];
    const float* bias = p.bias[z];
    unsigned short* out = p.out[z];
    const float oscale = p.scale[z];

    const int t = threadIdx.x, lane = t & 63, w = t >> 6;
    const int lr = lane & 15, lh = lane >> 4;
    const int m0 = blockIdx.y * 128, n0 = blockIdx.x * 128;
    const int wm = (w >> 1) * 64, wn = (w & 1) * 64;
    const int wbase = (t & 0xC0) * 8;

    f32x4 acc[4][4];
#pragma unroll
    for (int i = 0; i < 4; ++i)
#pragma unroll
        for (int j = 0; j < 4; ++j)
#pragma unroll
            for (int e = 0; e < 4; ++e) acc[i][j][e] = 0.0f;

    for (int kt = 0; kt < 16; ++kt) {
        const int k0 = kt << 6;
        __syncthreads();   // all waves done reading previous tile
#pragma unroll
        for (int q = 0; q < 4; ++q) {
            int lin = q * 256 + t;
            int row = lin >> 3, sc = (lin ^ (lin >> 3)) & 7;
            gload16(A + (size_t)(m0 + row) * 1024 + k0 + sc * 8, &As[q * 2048 + wbase]);
        }
#pragma unroll
        for (int q = 0; q < 4; ++q) {
            int lin = q * 256 + t;
            int row = lin >> 3, sc = (lin ^ (lin >> 3)) & 7;
            gload16(Bt + (size_t)(n0 + row) * 1024 + k0 + sc * 8, &Bs[q * 2048 + wbase]);
        }
        __syncthreads();   // vmcnt(0) drained per-wave before barrier -> tile ready
#pragma unroll
        for (int kb = 0; kb < 2; ++kb) {
            bf16x8 a[4], b[4];
#pragma unroll
            for (int i = 0; i < 4; ++i) a[i] = frag_swz(As, wm + i * 16 + lr, kb * 4 + lh);
#pragma unroll
            for (int j = 0; j < 4; ++j) b[j] = frag_swz(Bs, wn + j * 16 + lr, kb * 4 + lh);
#pragma unroll
            for (int i = 0; i < 4; ++i)
#pragma unroll
                for (int j = 0; j < 4; ++j)
                    acc[i][j] = MFMA16(a[i], b[j], acc[i][j]);
        }
    }

#pragma unroll
    for (int i = 0; i < 4; ++i) {
#pragma unroll
        for (int j = 0; j < 4; ++j) {
            const int gcol = n0 + wn + j * 16 + lr;
            const float bv = bias[gcol];
            const int h_ = gcol >> 6, hd_ = gcol & 63;
            if (z == 2) {
                const int grow0 = m0 + wm + i * 16 + lh * 4;
                const int b_ = grow0 >> 11, s_ = grow0 & 2047;
                u16x4 pk;
#pragma unroll
                for (int r = 0; r < 4; ++r) pk[r] = f2bf((acc[i][j][r] + bv) * oscale);
                *(u16x4*)(out + (((size_t)((b_ * 16 + h_) * 64 + hd_)) << 11) + s_) = pk;
            } else {
#pragma unroll
                for (int r = 0; r < 4; ++r) {
                    const int grow = m0 + wm + i * 16 + lh * 4 + r;
                    const int b_ = grow >> 11, s_ = grow & 2047;
                    out[((size_t)((b_ * 16 + h_) * 2048 + s_) << 6) + hd_] =
                        f2bf((acc[i][j][r] + bv) * oscale);
                }
            }
        }
    }
}

// ---------------------------------------------------------------------------
// O-projection split-K half: grid (8, 32, 2); z = K-half (512 each).
// 128x128 tile, single-buffered 32KB, fp32 partial out (bias folded into z=0).
// ---------------------------------------------------------------------------
__global__ __launch_bounds__(256, 3)
void gemm_o_half(const unsigned short* __restrict__ A, const unsigned short* __restrict__ Bt,
                 const float* __restrict__ bias, float* __restrict__ P0, float* __restrict__ P1)
{
    __shared__ __align__(16) unsigned short As[128 * 64];
    __shared__ __align__(16) unsigned short Bs[128 * 64];

    const int z = blockIdx.z;
    float* Part = z ? P1 : P0;
    const int t = threadIdx.x, lane = t & 63, w = t >> 6;
    const int lr = lane & 15, lh = lane >> 4;
    const int m0 = blockIdx.y * 128, n0 = blockIdx.x * 128;
    const int wm = (w >> 1) * 64, wn = (w & 1) * 64;
    const int wbase = (t & 0xC0) * 8;
    const int kbase = z << 9;

    f32x4 acc[4][4];
#pragma unroll
    for (int i = 0; i < 4; ++i)
#pragma unroll
        for (int j = 0; j < 4; ++j)
#pragma unroll
            for (int e = 0; e < 4; ++e) acc[i][j][e] = 0.0f;

    for (int kt = 0; kt < 8; ++kt) {
        const int k0 = kbase + (kt << 6);
        __syncthreads();
#pragma unroll
        for (int q = 0; q < 4; ++q) {
            int lin = q * 256 + t;
            int row = lin >> 3, sc = (lin ^ (lin >> 3)) & 7;
            gload16(A + (size_t)(m0 + row) * 1024 + k0 + sc * 8, &As[q * 2048 + wbase]);
        }
#pragma unroll
        for (int q = 0; q < 4; ++q) {
            int lin = q * 256 + t;
            int row = lin >> 3, sc = (lin ^ (lin >> 3)) & 7;
            gload16(Bt + (size_t)(n0 + row) * 1024 + k0 + sc * 8, &Bs[q * 2048 + wbase]);
        }
        __syncthreads();
#pragma unroll
        for (int kb = 0; kb < 2; ++kb) {
            bf16x8 a[4], b[4];
#pragma unroll
            for (int i = 0; i < 4; ++i) a[i] = frag_swz(As, wm + i * 16 + lr, kb * 4 + lh);
#pragma unroll
            for (int j = 0; j < 4; ++j) b[j] = frag_swz(Bs, wn + j * 16 + lr, kb * 4 + lh);
#pragma unroll
            for (int i = 0; i < 4; ++i)
#pragma unroll
                for (int j = 0; j < 4; ++j)
                    acc[i][j] = MFMA16(a[i], b[j], acc[i][j]);
        }
    }

#pragma unroll
    for (int i = 0; i < 4; ++i) {
#pragma unroll
        for (int j = 0; j < 4; ++j) {
            const int gcol = n0 + wn + j * 16 + lr;
            const float bv = z ? 0.0f : bias[gcol];
#pragma unroll
            for (int r = 0; r < 4; ++r) {
                const int grow = m0 + wm + i * 16 + lh * 4 + r;
                Part[(size_t)grow * 1024 + gcol] = acc[i][j][r] + bv;
            }
        }
    }
}

// out = P0 + P1 (4Mi fp32)
__global__ void add2_kernel(const float* __restrict__ P0, const float* __restrict__ P1,
                            float* __restrict__ out) {
    const size_t i = ((size_t)blockIdx.x * 256 + threadIdx.x) * 8;
    f32x4 a0 = *(const f32x4*)(P0 + i),     a1 = *(const f32x4*)(P0 + i + 4);
    f32x4 b0 = *(const f32x4*)(P1 + i),     b1 = *(const f32x4*)(P1 + i + 4);
#pragma unroll
    for (int j = 0; j < 4; ++j) { a0[j] += b0[j]; a1[j] += b1[j]; }
    *(f32x4*)(out + i) = a0;
    *(f32x4*)(out + i + 4) = a1;
}

// ---------------------------------------------------------------------------
// Causal flash attention, exp2 domain. 512-thread blocks (8 waves).
// Block = (bh, q-tile pair {2p, 2p+1}); waves 0-3 own tile 2p, waves 4-7 own
// tile 2p+1, sharing the staged K/V tiles. Q,K (B,H,S,HD); Vt (B,H,HD,S).
// ---------------------------------------------------------------------------
__global__ __launch_bounds__(512, 4)
void attn_kernel(const unsigned short* __restrict__ Qp,
                 const unsigned short* __restrict__ Kp,
                 const unsigned short* __restrict__ Vtp,
                 unsigned short* __restrict__ Cp)
{
    __shared__ __align__(16) unsigned short Ks[2][64 * 64];
    __shared__ __align__(16) unsigned short Vs[2][64 * 64];
    __shared__ __align__(16) unsigned short Pl[8][16 * 64];

    const int t = threadIdx.x, lane = t & 63, w = t >> 6;      // w: 0..7
    const int lr = lane & 15, lh = lane >> 4;
    const int wbase = (t & 0x1C0) * 8;                          // wave elem base (w*512)

    const int g = blockIdx.x;                 // 0..511
    const int local = g >> 3;                 // 0..63
    const int bh = (g & 7) * 4 + (local >> 4);    // bh pinned to XCD (g&7)
    const int p = local & 15;                 // pair id: q-tiles {2p, 2p+1}
    const int grp = w >> 2;                   // 0/1 -> which q-tile this wave owns
    const int qt = 2 * p + grp;
    const int q0w = qt * 64 + (w & 3) * 16;   // this wave's 16 q-rows
    const int ntiles = 2 * p + 2;             // kv tiles staged by the block
    const int mytiles = qt + 1;               // kv tiles this wave computes

    const size_t baseQK = (size_t)bh * (2048 * 64);
    const size_t baseV  = (size_t)bh * (64 * 2048);

    auto stageKV = [&](int buf, int kv0) {
        const int row = t >> 3;                      // 0..63
        const int sc = (t ^ (t >> 3)) & 7;           // source chunk XOR-swizzle
        gload16(Kp + baseQK + (size_t)(kv0 + row) * 64 + sc * 8, &Ks[buf][wbase]);
        gload16(Vtp + baseV + (size_t)row * 2048 + kv0 + sc * 8, &Vs[buf][wbase]);
    };

    unsigned short* pl = &Pl[w][0];
    const int b_ = bh >> 4, h_ = bh & 15;

    const unsigned short* qrow = Qp + baseQK + (size_t)(q0w + lr) * 64 + lh * 8;
    const bf16x8 qf0 = *(const bf16x8*)qrow;
    const bf16x8 qf1 = *(const bf16x8*)(qrow + 32);

    f32x4 o[4]; float m[4], l[4];
#pragma unroll
    for (int i = 0; i < 4; ++i) {
#pragma unroll
        for (int e = 0; e < 4; ++e) o[i][e] = 0.0f;
        m[i] = -INFINITY; l[i] = 0.0f;
    }

    stageKV(0, 0);
    for (int tt = 0; tt < ntiles; ++tt) {
        __syncthreads();              // drains vmcnt: stage(tt) complete
        if (tt + 1 < ntiles) stageKV((tt + 1) & 1, (tt + 1) * 64);
        if (tt < mytiles) {           // wave-uniform guard
            const unsigned short* ks = Ks[tt & 1];
            const unsigned short* vs = Vs[tt & 1];

            // ---- scores (log2 units; Q pre-scaled) ----
            f32x4 s[4];
            __builtin_amdgcn_s_setprio(1);
#pragma unroll
            for (int c = 0; c < 4; ++c) {
#pragma unroll
                for (int e = 0; e < 4; ++e) s[c][e] = 0.0f;
                s[c] = MFMA16(qf0, frag_swz(ks, c * 16 + lr, lh), s[c]);
                s[c] = MFMA16(qf1, frag_swz(ks, c * 16 + lr, 4 + lh), s[c]);
            }
            __builtin_amdgcn_s_setprio(0);

            // ---- online softmax: lazy max + deferred l-reduction ----
            const bool diag = (tt == qt);
            const int kv0 = tt * 64;
#pragma unroll
            for (int r = 0; r < 4; ++r) {
                const int row = lh * 4 + r;
                const int grow = q0w + row;
                float tv[4];
#pragma unroll
                for (int c = 0; c < 4; ++c) {
                    float x = s[c][r];
                    if (diag && (kv0 + c * 16 + lr > grow)) x = -1e30f;
                    tv[c] = x;
                }
                const float lmax = fmaxf(fmaxf(tv[0], tv[1]), fmaxf(tv[2], tv[3]));
                if (!__all(lmax <= m[r] + 11.0f)) {
                    float cm = lmax;
                    cm = fmaxf(cm, __shfl_xor(cm, 1));
                    cm = fmaxf(cm, __shfl_xor(cm, 2));
                    cm = fmaxf(cm, __shfl_xor(cm, 4));
                    cm = fmaxf(cm, __shfl_xor(cm, 8));
                    const float mn = fmaxf(m[r], cm);
                    const float al = exp2fast(m[r] - mn);
#pragma unroll
                    for (int hc = 0; hc < 4; ++hc) o[hc][r] *= al;
                    l[r] *= al;
                    m[r] = mn;
                }
                float rs = 0.0f;
#pragma unroll
                for (int c = 0; c < 4; ++c) {
                    const float pv = exp2fast(tv[c] - m[r]);
                    rs += pv;
                    *(__bf16*)((char*)pl + row * 128 +
                        ((c * 32 + lr * 2) ^ ((row & 7) << 4))) = (__bf16)pv;
                }
                l[r] += rs;   // per-lane partial; reduced once at epilogue
            }

            // ---- PV ----
            const bf16x8 pf0 = frag_swz(pl, lr, lh);
            const bf16x8 pf1 = frag_swz(pl, lr, 4 + lh);
            __builtin_amdgcn_s_setprio(1);
#pragma unroll
            for (int hc = 0; hc < 4; ++hc) {
                o[hc] = MFMA16(pf0, frag_swz(vs, hc * 16 + lr, lh), o[hc]);
                o[hc] = MFMA16(pf1, frag_swz(vs, hc * 16 + lr, 4 + lh), o[hc]);
            }
            __builtin_amdgcn_s_setprio(0);
        }
    }

    // ---- epilogue ----
#pragma unroll
    for (int r = 0; r < 4; ++r) {
        float sum = l[r];
        sum += __shfl_xor(sum, 1);
        sum += __shfl_xor(sum, 2);
        sum += __shfl_xor(sum, 4);
        sum += __shfl_xor(sum, 8);
        const float inv = 1.0f / sum;
        const int srow = q0w + lh * 4 + r;
#pragma unroll
        for (int hc = 0; hc < 4; ++hc) {
            Cp[(size_t)(b_ * 2048 + srow) * 1024 + h_ * 64 + hc * 16 + lr] =
                f2bf(o[hc][r] * inv);
        }
    }
}

// ---------------------------------------------------------------------------
extern "C" void kernel_launch(void* const* d_in, const int* in_sizes, int n_in,
                              void* d_out, int out_size, void* d_ws, size_t ws_size,
                              hipStream_t stream)
{
    const float* queries = (const float*)d_in[0];
    const float* keys    = (const float*)d_in[1];
    const float* values  = (const float*)d_in[2];
    const float* W_q = (const float*)d_in[4];
    const float* b_q = (const float*)d_in[5];
    const float* W_k = (const float*)d_in[6];
    const float* b_k = (const float*)d_in[7];
    const float* W_v = (const float*)d_in[8];
    const float* b_v = (const float*)d_in[9];
    const float* W_o = (const float*)d_in[10];
    const float* b_o = (const float*)d_in[11];

    constexpr size_t NE = (size_t)4 * 1024 * 1024;  // elems per (B,S,D) tensor
    constexpr size_t WE = (size_t)1024 * 1024;
    unsigned short* qc  = (unsigned short*)d_ws;
    unsigned short* kc  = qc + NE;
    unsigned short* vc  = kc + NE;
    unsigned short* wqT = vc + NE;
    unsigned short* wkT = wqT + WE;
    unsigned short* wvT = wkT + WE;
    unsigned short* woT = wvT + WE;
    unsigned short* Qb  = woT + WE;
    unsigned short* Kb  = Qb + NE;
    unsigned short* Vtb = Kb + NE;
    unsigned short* Cb  = Vtb + NE;
    // split-K partials alias buffers that are dead by the time gemm_o runs:
    float* P0 = (float*)qc;   // qc+kc region (16MB), dead after gemm_qkv
    float* P1 = (float*)Qb;   // Qb+Kb region (16MB), dead after attn

    const float qscale = 0.125f * 1.44269504f;   // 1/sqrt(64) * log2(e)

    PrepArgs pa;
    pa.act[0] = queries; pa.act[1] = keys; pa.act[2] = values;
    pa.actout[0] = qc; pa.actout[1] = kc; pa.actout[2] = vc;
    pa.W[0] = W_q; pa.W[1] = W_k; pa.W[2] = W_v; pa.W[3] = W_o;
    pa.Wt[0] = wqT; pa.Wt[1] = wkT; pa.Wt[2] = wvT; pa.Wt[3] = woT;
    prep_kernel<<<7168, 256, 0, stream>>>(pa);

    QkvArgs qp;
    qp.A[0] = qc;  qp.Wt[0] = wqT; qp.bias[0] = b_q; qp.out[0] = Qb;  qp.scale[0] = qscale;
    qp.A[1] = kc;  qp.Wt[1] = wkT; qp.bias[1] = b_k; qp.out[1] = Kb;  qp.scale[1] = 1.0f;
    qp.A[2] = vc;  qp.Wt[2] = wvT; qp.bias[2] = b_v; qp.out[2] = Vtb; qp.scale[2] = 1.0f;
    gemm_qkv<<<dim3(8, 32, 3), 256, 0, stream>>>(qp);

    attn_kernel<<<512, 512, 0, stream>>>(Qb, Kb, Vtb, Cb);

    gemm_o_half<<<dim3(8, 32, 2), 256, 0, stream>>>(Cb, woT, b_o, P0, P1);
    add2_kernel<<<2048, 256, 0, stream>>>(P0, P1, (float*)d_out);
}

// Round 6
// 244.724 us; speedup vs baseline: 1.2010x; 1.2010x over previous
//
#include <hip/hip_runtime.h>
#include <hip/hip_bf16.h>
#include <math.h>

typedef __bf16 bf16x8 __attribute__((ext_vector_type(8)));
typedef float f32x4 __attribute__((ext_vector_type(4)));
typedef unsigned short u16x8 __attribute__((ext_vector_type(8)));
typedef unsigned short u16x4 __attribute__((ext_vector_type(4)));

struct FalseC { static constexpr bool v = false; };
struct TrueC  { static constexpr bool v = true;  };

static __device__ __forceinline__ unsigned short f2bf(float f) {
    union { float f; unsigned u; } v; v.f = f;
    unsigned r = v.u + 0x7fffu + ((v.u >> 16) & 1u);
    return (unsigned short)(r >> 16);
}

static __device__ __forceinline__ float exp2fast(float x) {
    return __builtin_exp2f(x);   // v_exp_f32; avoids glibc __exp2f macro clash
}

static __device__ __forceinline__ void gload16(const void* g, void* l) {
    __builtin_amdgcn_global_load_lds((const __attribute__((address_space(1))) unsigned int*)g,
                                     (__attribute__((address_space(3))) unsigned int*)l, 16, 0, 0);
}

#define MFMA16(a, b, c) __builtin_amdgcn_mfma_f32_16x16x32_bf16((a), (b), (c), 0, 0, 0)

// read a bf16x8 fragment from a chunk-XOR-swizzled tile with 128B rows
static __device__ __forceinline__ bf16x8 frag_swz(const unsigned short* base, int row, int chunk) {
    return *(const bf16x8*)((const char*)base + row * 128 + (((chunk ^ row) & 7) << 4));
}

// ---------------------------------------------------------------------------
// prep: fused fp32->bf16 for 3 activation tensors (blocks 0..6143) and
// W[k][n] -> Wt bf16 [n][k] transpose for 4 weights (blocks 6144..7167).
// ---------------------------------------------------------------------------
struct PrepArgs {
    const float* act[3]; unsigned short* actout[3];
    const float* W[4];   unsigned short* Wt[4];
};

__global__ void prep_kernel(PrepArgs a) {
    __shared__ __align__(16) unsigned short Ws[64][66];
    const int b = blockIdx.x, t = threadIdx.x;
    if (b < 6144) {
        const int sel = b >> 11;
        const size_t i = (((size_t)(b & 2047)) * 256 + t) * 8;
        const float* in = a.act[sel];
        f32x4 v0 = *(const f32x4*)(in + i);
        f32x4 v1 = *(const f32x4*)(in + i + 4);
        u16x8 o;
#pragma unroll
        for (int j = 0; j < 4; ++j) { o[j] = f2bf(v0[j]); o[j + 4] = f2bf(v1[j]); }
        *(u16x8*)(a.actout[sel] + i) = o;
        return;
    }
    const int idx = b - 6144;              // 0..1023
    const int z = idx >> 8;                // weight id
    const int rem = idx & 255;
    const int c0 = (rem & 15) * 64;        // n base
    const int r0 = (rem >> 4) * 64;        // k base
    const float* W = a.W[z];
    unsigned short* Wt = a.Wt[z];
#pragma unroll
    for (int p = 0; p < 4; ++p) {
        int lin = p * 256 + t;
        int r = lin >> 4, cc = (lin & 15) * 4;
        f32x4 v = *(const f32x4*)(W + (size_t)(r0 + r) * 1024 + c0 + cc);
#pragma unroll
        for (int j = 0; j < 4; ++j) Ws[r][cc + j] = f2bf(v[j]);
    }
    __syncthreads();
#pragma unroll
    for (int p = 0; p < 2; ++p) {
        int lin = p * 256 + t;
        int n = lin >> 3, kc = (lin & 7) * 8;
        u16x8 o;
#pragma unroll
        for (int j = 0; j < 8; ++j) o[j] = Ws[kc + j][n];
        *(u16x8*)(Wt + (size_t)(c0 + n) * 1024 + r0 + kc) = o;
    }
}

// ---------------------------------------------------------------------------
// Fused QKV projection: grid (8, 32, 3); z selects {Q,K,V}.
// 128x128 tile, BK=64, single-buffered LDS (32KB) -> 3 blocks/CU.
// z<2: out bf16 (B,H,S,HD) scaled; z==2: out bf16 (B,H,HD,S).
// ---------------------------------------------------------------------------
struct QkvArgs {
    const unsigned short* A[3];
    const unsigned short* Wt[3];
    const float* bias[3];
    unsigned short* out[3];
    float scale[3];
};

__global__ __launch_bounds__(256, 3)
void gemm_qkv(QkvArgs p)
{
    __shared__ __align__(16) unsigned short As[128 * 64];
    __shared__ __align__(16) unsigned short Bs[128 * 64];

    const int z = blockIdx.z;
    const unsigned short* A  = p.A[z];
    const unsigned short* Bt = p.Wt[z];
    const float* bias = p.bias[z];
    unsigned short* out = p.out[z];
    const float oscale = p.scale[z];

    const int t = threadIdx.x, lane = t & 63, w = t >> 6;
    const int lr = lane & 15, lh = lane >> 4;
    const int m0 = blockIdx.y * 128, n0 = blockIdx.x * 128;
    const int wm = (w >> 1) * 64, wn = (w & 1) * 64;
    const int wbase = (t & 0xC0) * 8;

    f32x4 acc[4][4];
#pragma unroll
    for (int i = 0; i < 4; ++i)
#pragma unroll
        for (int j = 0; j < 4; ++j)
#pragma unroll
            for (int e = 0; e < 4; ++e) acc[i][j][e] = 0.0f;

    for (int kt = 0; kt < 16; ++kt) {
        const int k0 = kt << 6;
        __syncthreads();   // all waves done reading previous tile
#pragma unroll
        for (int q = 0; q < 4; ++q) {
            int lin = q * 256 + t;
            int row = lin >> 3, sc = (lin ^ (lin >> 3)) & 7;
            gload16(A + (size_t)(m0 + row) * 1024 + k0 + sc * 8, &As[q * 2048 + wbase]);
        }
#pragma unroll
        for (int q = 0; q < 4; ++q) {
            int lin = q * 256 + t;
            int row = lin >> 3, sc = (lin ^ (lin >> 3)) & 7;
            gload16(Bt + (size_t)(n0 + row) * 1024 + k0 + sc * 8, &Bs[q * 2048 + wbase]);
        }
        __syncthreads();   // vmcnt(0) drained per-wave before barrier -> tile ready
#pragma unroll
        for (int kb = 0; kb < 2; ++kb) {
            bf16x8 a[4], b[4];
#pragma unroll
            for (int i = 0; i < 4; ++i) a[i] = frag_swz(As, wm + i * 16 + lr, kb * 4 + lh);
#pragma unroll
            for (int j = 0; j < 4; ++j) b[j] = frag_swz(Bs, wn + j * 16 + lr, kb * 4 + lh);
#pragma unroll
            for (int i = 0; i < 4; ++i)
#pragma unroll
                for (int j = 0; j < 4; ++j)
                    acc[i][j] = MFMA16(a[i], b[j], acc[i][j]);
        }
    }

#pragma unroll
    for (int i = 0; i < 4; ++i) {
#pragma unroll
        for (int j = 0; j < 4; ++j) {
            const int gcol = n0 + wn + j * 16 + lr;
            const float bv = bias[gcol];
            const int h_ = gcol >> 6, hd_ = gcol & 63;
            if (z == 2) {
                const int grow0 = m0 + wm + i * 16 + lh * 4;
                const int b_ = grow0 >> 11, s_ = grow0 & 2047;
                u16x4 pk;
#pragma unroll
                for (int r = 0; r < 4; ++r) pk[r] = f2bf((acc[i][j][r] + bv) * oscale);
                *(u16x4*)(out + (((size_t)((b_ * 16 + h_) * 64 + hd_)) << 11) + s_) = pk;
            } else {
#pragma unroll
                for (int r = 0; r < 4; ++r) {
                    const int grow = m0 + wm + i * 16 + lh * 4 + r;
                    const int b_ = grow >> 11, s_ = grow & 2047;
                    out[((size_t)((b_ * 16 + h_) * 2048 + s_) << 6) + hd_] =
                        f2bf((acc[i][j][r] + bv) * oscale);
                }
            }
        }
    }
}

// ---------------------------------------------------------------------------
// O-projection split-K half: grid (8, 32, 2); z = K-half (512 each).
// 128x128 tile, single-buffered 32KB, fp32 partial out (bias folded into z=0).
// ---------------------------------------------------------------------------
__global__ __launch_bounds__(256, 3)
void gemm_o_half(const unsigned short* __restrict__ A, const unsigned short* __restrict__ Bt,
                 const float* __restrict__ bias, float* __restrict__ P0, float* __restrict__ P1)
{
    __shared__ __align__(16) unsigned short As[128 * 64];
    __shared__ __align__(16) unsigned short Bs[128 * 64];

    const int z = blockIdx.z;
    float* Part = z ? P1 : P0;
    const int t = threadIdx.x, lane = t & 63, w = t >> 6;
    const int lr = lane & 15, lh = lane >> 4;
    const int m0 = blockIdx.y * 128, n0 = blockIdx.x * 128;
    const int wm = (w >> 1) * 64, wn = (w & 1) * 64;
    const int wbase = (t & 0xC0) * 8;
    const int kbase = z << 9;

    f32x4 acc[4][4];
#pragma unroll
    for (int i = 0; i < 4; ++i)
#pragma unroll
        for (int j = 0; j < 4; ++j)
#pragma unroll
            for (int e = 0; e < 4; ++e) acc[i][j][e] = 0.0f;

    for (int kt = 0; kt < 8; ++kt) {
        const int k0 = kbase + (kt << 6);
        __syncthreads();
#pragma unroll
        for (int q = 0; q < 4; ++q) {
            int lin = q * 256 + t;
            int row = lin >> 3, sc = (lin ^ (lin >> 3)) & 7;
            gload16(A + (size_t)(m0 + row) * 1024 + k0 + sc * 8, &As[q * 2048 + wbase]);
        }
#pragma unroll
        for (int q = 0; q < 4; ++q) {
            int lin = q * 256 + t;
            int row = lin >> 3, sc = (lin ^ (lin >> 3)) & 7;
            gload16(Bt + (size_t)(n0 + row) * 1024 + k0 + sc * 8, &Bs[q * 2048 + wbase]);
        }
        __syncthreads();
#pragma unroll
        for (int kb = 0; kb < 2; ++kb) {
            bf16x8 a[4], b[4];
#pragma unroll
            for (int i = 0; i < 4; ++i) a[i] = frag_swz(As, wm + i * 16 + lr, kb * 4 + lh);
#pragma unroll
            for (int j = 0; j < 4; ++j) b[j] = frag_swz(Bs, wn + j * 16 + lr, kb * 4 + lh);
#pragma unroll
            for (int i = 0; i < 4; ++i)
#pragma unroll
                for (int j = 0; j < 4; ++j)
                    acc[i][j] = MFMA16(a[i], b[j], acc[i][j]);
        }
    }

#pragma unroll
    for (int i = 0; i < 4; ++i) {
#pragma unroll
        for (int j = 0; j < 4; ++j) {
            const int gcol = n0 + wn + j * 16 + lr;
            const float bv = z ? 0.0f : bias[gcol];
#pragma unroll
            for (int r = 0; r < 4; ++r) {
                const int grow = m0 + wm + i * 16 + lh * 4 + r;
                Part[(size_t)grow * 1024 + gcol] = acc[i][j][r] + bv;
            }
        }
    }
}

// out = P0 + P1 (4Mi fp32)
__global__ void add2_kernel(const float* __restrict__ P0, const float* __restrict__ P1,
                            float* __restrict__ out) {
    const size_t i = ((size_t)blockIdx.x * 256 + threadIdx.x) * 8;
    f32x4 a0 = *(const f32x4*)(P0 + i),     a1 = *(const f32x4*)(P0 + i + 4);
    f32x4 b0 = *(const f32x4*)(P1 + i),     b1 = *(const f32x4*)(P1 + i + 4);
#pragma unroll
    for (int j = 0; j < 4; ++j) { a0[j] += b0[j]; a1[j] += b1[j]; }
    *(f32x4*)(out + i) = a0;
    *(f32x4*)(out + i + 4) = a1;
}

// ---------------------------------------------------------------------------
// Causal flash attention, exp2 domain (scale*log2e folded into Q projection).
// Q,K bf16 (B,H,S,HD); Vt bf16 (B,H,HD,S); out ctx bf16 (B,S,D).
// 512 blocks of 4 waves: block handles q-tile pair (x, 31-x) -> 33 balanced
// kv-iters. Diagonal tile peeled (mask VALU off the hot path). XCD-pinned bh.
// ---------------------------------------------------------------------------
__global__ __launch_bounds__(256, 2)
void attn_kernel(const unsigned short* __restrict__ Qp,
                 const unsigned short* __restrict__ Kp,
                 const unsigned short* __restrict__ Vtp,
                 unsigned short* __restrict__ Cp)
{
    __shared__ __align__(16) unsigned short Ks[2][64 * 64];
    __shared__ __align__(16) unsigned short Vs[2][64 * 64];
    __shared__ __align__(16) unsigned short Pl[4][16 * 64];

    const int t = threadIdx.x, lane = t & 63, w = t >> 6;
    const int lr = lane & 15, lh = lane >> 4;
    const int wbase = (t & 0xC0) * 8;

    const int g = blockIdx.x;            // 0..511
    const int local = g >> 3;            // 0..63
    const int bh = (g & 7) * 4 + (local >> 4);   // bh pinned to XCD (g&7)
    const int qA = local & 15;           // pair (qA, 31-qA) of 64-row q-tiles
    const size_t baseQK = (size_t)bh * (2048 * 64);
    const size_t baseV  = (size_t)bh * (64 * 2048);

    auto stageKV = [&](int buf, int kv0) {
#pragma unroll
        for (int q = 0; q < 2; ++q) {
            int lin = q * 256 + t;
            int row = lin >> 3, sc = (lin ^ (lin >> 3)) & 7;
            gload16(Kp + baseQK + (size_t)(kv0 + row) * 64 + sc * 8, &Ks[buf][q * 2048 + wbase]);
        }
#pragma unroll
        for (int q = 0; q < 2; ++q) {
            int lin = q * 256 + t;
            int row = lin >> 3, sc = (lin ^ (lin >> 3)) & 7;
            gload16(Vtp + baseV + (size_t)row * 2048 + kv0 + sc * 8, &Vs[buf][q * 2048 + wbase]);
        }
    };

    unsigned short* pl = &Pl[w][0];
    const int b_ = bh >> 4, h_ = bh & 15;

    for (int qi = 0; qi < 2; ++qi) {
        const int qt = qi ? (31 - qA) : qA;
        const int q0w = qt * 64 + w * 16;          // this wave's 16 q-rows

        const unsigned short* qrow = Qp + baseQK + (size_t)(q0w + lr) * 64 + lh * 8;
        const bf16x8 qf0 = *(const bf16x8*)qrow;
        const bf16x8 qf1 = *(const bf16x8*)(qrow + 32);

        f32x4 o[4]; float m[4], l[4];
#pragma unroll
        for (int i = 0; i < 4; ++i) {
#pragma unroll
            for (int e = 0; e < 4; ++e) o[i][e] = 0.0f;
            m[i] = -INFINITY; l[i] = 0.0f;
        }

        // one kv tile: scores -> online softmax -> PV. DIAG: apply causal mask.
        auto tile_body = [&](auto dc, const unsigned short* ks, const unsigned short* vs) {
            f32x4 s[4];
#pragma unroll
            for (int c = 0; c < 4; ++c) {
#pragma unroll
                for (int e = 0; e < 4; ++e) s[c][e] = 0.0f;
                s[c] = MFMA16(qf0, frag_swz(ks, c * 16 + lr, lh), s[c]);
                s[c] = MFMA16(qf1, frag_swz(ks, c * 16 + lr, 4 + lh), s[c]);
            }
#pragma unroll
            for (int r = 0; r < 4; ++r) {
                const int row = lh * 4 + r;
                float tv[4];
#pragma unroll
                for (int c = 0; c < 4; ++c) {
                    float x = s[c][r];
                    if constexpr (decltype(dc)::v) {
                        // diag tile: kv base == qt*64; mask kv col > q row
                        if (c * 16 + lr > (w * 16 + row)) x = -1e30f;
                    }
                    tv[c] = x;
                }
                const float lmax = fmaxf(fmaxf(tv[0], tv[1]), fmaxf(tv[2], tv[3]));
                if (!__all(lmax <= m[r] + 11.0f)) {
                    float cm = lmax;
                    cm = fmaxf(cm, __shfl_xor(cm, 1));
                    cm = fmaxf(cm, __shfl_xor(cm, 2));
                    cm = fmaxf(cm, __shfl_xor(cm, 4));
                    cm = fmaxf(cm, __shfl_xor(cm, 8));
                    const float mn = fmaxf(m[r], cm);
                    const float al = exp2fast(m[r] - mn);
#pragma unroll
                    for (int hc = 0; hc < 4; ++hc) o[hc][r] *= al;
                    l[r] *= al;
                    m[r] = mn;
                }
                float rs = 0.0f;
#pragma unroll
                for (int c = 0; c < 4; ++c) {
                    const float pv = exp2fast(tv[c] - m[r]);
                    rs += pv;
                    *(__bf16*)((char*)pl + row * 128 +
                        ((c * 32 + lr * 2) ^ ((row & 7) << 4))) = (__bf16)pv;
                }
                l[r] += rs;   // per-lane partial; reduced once at epilogue
            }
            const bf16x8 pf0 = frag_swz(pl, lr, lh);
            const bf16x8 pf1 = frag_swz(pl, lr, 4 + lh);
#pragma unroll
            for (int hc = 0; hc < 4; ++hc) {
                o[hc] = MFMA16(pf0, frag_swz(vs, hc * 16 + lr, lh), o[hc]);
                o[hc] = MFMA16(pf1, frag_swz(vs, hc * 16 + lr, 4 + lh), o[hc]);
            }
        };

        __syncthreads();                  // everyone done with previous buffers
        stageKV(0, 0);
        for (int tt = 0; tt < qt; ++tt) { // non-diag tiles (mask-free)
            __syncthreads();              // drains vmcnt: stage(tt) complete
            stageKV((tt + 1) & 1, (tt + 1) * 64);
            tile_body(FalseC{}, Ks[tt & 1], Vs[tt & 1]);
        }
        __syncthreads();                  // stage(qt) complete
        tile_body(TrueC{}, Ks[qt & 1], Vs[qt & 1]);   // peeled diagonal tile

        // ---- epilogue for this q-tile ----
#pragma unroll
        for (int r = 0; r < 4; ++r) {
            float sum = l[r];
            sum += __shfl_xor(sum, 1);
            sum += __shfl_xor(sum, 2);
            sum += __shfl_xor(sum, 4);
            sum += __shfl_xor(sum, 8);
            const float inv = 1.0f / sum;
            const int srow = q0w + lh * 4 + r;
#pragma unroll
            for (int hc = 0; hc < 4; ++hc) {
                Cp[(size_t)(b_ * 2048 + srow) * 1024 + h_ * 64 + hc * 16 + lr] =
                    f2bf(o[hc][r] * inv);
            }
        }
    }
}

// ---------------------------------------------------------------------------
extern "C" void kernel_launch(void* const* d_in, const int* in_sizes, int n_in,
                              void* d_out, int out_size, void* d_ws, size_t ws_size,
                              hipStream_t stream)
{
    const float* queries = (const float*)d_in[0];
    const float* keys    = (const float*)d_in[1];
    const float* values  = (const float*)d_in[2];
    const float* W_q = (const float*)d_in[4];
    const float* b_q = (const float*)d_in[5];
    const float* W_k = (const float*)d_in[6];
    const float* b_k = (const float*)d_in[7];
    const float* W_v = (const float*)d_in[8];
    const float* b_v = (const float*)d_in[9];
    const float* W_o = (const float*)d_in[10];
    const float* b_o = (const float*)d_in[11];

    constexpr size_t NE = (size_t)4 * 1024 * 1024;  // elems per (B,S,D) tensor
    constexpr size_t WE = (size_t)1024 * 1024;
    unsigned short* qc  = (unsigned short*)d_ws;
    unsigned short* kc  = qc + NE;
    unsigned short* vc  = kc + NE;
    unsigned short* wqT = vc + NE;
    unsigned short* wkT = wqT + WE;
    unsigned short* wvT = wkT + WE;
    unsigned short* woT = wvT + WE;
    unsigned short* Qb  = woT + WE;
    unsigned short* Kb  = Qb + NE;
    unsigned short* Vtb = Kb + NE;
    unsigned short* Cb  = Vtb + NE;
    // split-K partials alias buffers that are dead by the time gemm_o runs:
    float* P0 = (float*)qc;   // qc+kc region (16MB), dead after gemm_qkv
    float* P1 = (float*)Qb;   // Qb+Kb region (16MB), dead after attn

    const float qscale = 0.125f * 1.44269504f;   // 1/sqrt(64) * log2(e)

    PrepArgs pa;
    pa.act[0] = queries; pa.act[1] = keys; pa.act[2] = values;
    pa.actout[0] = qc; pa.actout[1] = kc; pa.actout[2] = vc;
    pa.W[0] = W_q; pa.W[1] = W_k; pa.W[2] = W_v; pa.W[3] = W_o;
    pa.Wt[0] = wqT; pa.Wt[1] = wkT; pa.Wt[2] = wvT; pa.Wt[3] = woT;
    prep_kernel<<<7168, 256, 0, stream>>>(pa);

    QkvArgs qp;
    qp.A[0] = qc;  qp.Wt[0] = wqT; qp.bias[0] = b_q; qp.out[0] = Qb;  qp.scale[0] = qscale;
    qp.A[1] = kc;  qp.Wt[1] = wkT; qp.bias[1] = b_k; qp.out[1] = Kb;  qp.scale[1] = 1.0f;
    qp.A[2] = vc;  qp.Wt[2] = wvT; qp.bias[2] = b_v; qp.out[2] = Vtb; qp.scale[2] = 1.0f;
    gemm_qkv<<<dim3(8, 32, 3), 256, 0, stream>>>(qp);

    attn_kernel<<<512, 256, 0, stream>>>(Qb, Kb, Vtb, Cb);

    gemm_o_half<<<dim3(8, 32, 2), 256, 0, stream>>>(Cb, woT, b_o, P0, P1);
    add2_kernel<<<2048, 256, 0, stream>>>(P0, P1, (float*)d_out);
}